// Round 3
// baseline (551.537 us; speedup 1.0000x reference)
//
#include <hip/hip_runtime.h>
#include <math.h>

// Problem constants (B=16, T=2048, DIM=512, N_EMBED=4096)
#define N_TOK   32768
#define N_CODE  4096
#define DIM     512

// Coarse MFMA tiling: block = 64 tokens x 2048 codes (one N-half)
#define CBM 64
#define NHALF 2048
#define CBN 256                   // codes per nt step
#define CBK 64                    // K chunk per staging round
#define NT_STEPS (NHALF / CBN)    // 8
#define KC_STEPS (DIM / CBK)      // 8
#define SPITCH 36                 // score strip pitch (floats), 16B aligned
#define BUFSZ 40960               // one LDS tile buffer: A 8KB + B 32KB

// ---------------------------------------------------------------------------
// Scheduler-movement-proof sync points (rule #18: register-only MFMA/VALU can
// cross inline asm despite "memory" clobber, dragging the compiler's lgkmcnt
// waits with them => a wave can pass a raw s_barrier with ds ops outstanding.
// Fix: sched_barrier(0) fences on both sides + explicit lgkmcnt drain).
#define SFENCE() __builtin_amdgcn_sched_barrier(0)

// drain own LDS ops, then barrier (WAR protection / LDS publish)
#define BARL() do { \
    SFENCE(); \
    asm volatile("s_waitcnt lgkmcnt(0)" ::: "memory"); \
    __builtin_amdgcn_s_barrier(); \
    SFENCE(); \
} while (0)

// publish staged tile: 10 newest vmem ops (next tile's DMA) stay in flight
#define BAR_PUB10() do { \
    SFENCE(); \
    asm volatile("s_waitcnt vmcnt(10)" ::: "memory"); \
    __builtin_amdgcn_s_barrier(); \
    SFENCE(); \
} while (0)

// publish final tile: nothing left in flight
#define BAR_PUB0() do { \
    SFENCE(); \
    asm volatile("s_waitcnt vmcnt(0)" ::: "memory"); \
    __builtin_amdgcn_s_barrier(); \
    SFENCE(); \
} while (0)

typedef __bf16 bf16x8 __attribute__((ext_vector_type(8)));
typedef float  f32x4  __attribute__((ext_vector_type(4)));

__device__ __forceinline__ unsigned short f32_to_bf16_rn(float f) {
    union { float f; unsigned int u; } c; c.f = f;
    unsigned int u = c.u;
    return (unsigned short)((u + 0x7FFFu + ((u >> 16) & 1u)) >> 16);
}

// ---------------------------------------------------------------------------
// numpy pairwise f32 sum over 512 contiguous elements (bit-exact), see R3.
__device__ __forceinline__ float pairwise_tree(const float* p) {
    float P[4];
#pragma unroll
    for (int b = 0; b < 4; ++b) {
        float t01 = __fadd_rn(p[b * 8 + 0], p[b * 8 + 1]);
        float t23 = __fadd_rn(p[b * 8 + 2], p[b * 8 + 3]);
        float t45 = __fadd_rn(p[b * 8 + 4], p[b * 8 + 5]);
        float t67 = __fadd_rn(p[b * 8 + 6], p[b * 8 + 7]);
        P[b] = __fadd_rn(__fadd_rn(t01, t23), __fadd_rn(t45, t67));
    }
    return __fadd_rn(__fadd_rn(P[0], P[1]), __fadd_rn(P[2], P[3]));
}

// ---------------------------------------------------------------------------
// K1: per-code f32-replicated norm + t3.
__global__ void norms_kernel(const float* __restrict__ embed,
                             float* __restrict__ n_f,
                             float* __restrict__ t3_f) {
    __shared__ float part[32];
    int j = blockIdx.x;
    int lane = threadIdx.x;
    const float* e = embed + (size_t)j * DIM;

    if (lane < 32) {
        int base = (lane >> 3) * 128 + (lane & 7);
        float v = e[base];
        float r = __fmul_rn(v, v);
#pragma unroll
        for (int i = 1; i < 16; ++i) {
            float u = e[base + 8 * i];
            r = __fadd_rn(r, __fmul_rn(u, u));
        }
        part[lane] = r;
    }
    __syncthreads();
    float S = pairwise_tree(part);
    float n = __fsqrt_rn(S);
    __syncthreads();

    if (lane < 32) {
        int base = (lane >> 3) * 128 + (lane & 7);
        float w0 = __fdiv_rn(e[base], n);
        float r = __fmul_rn(w0, w0);
#pragma unroll
        for (int i = 1; i < 16; ++i) {
            float w = __fdiv_rn(e[base + 8 * i], n);
            r = __fadd_rn(r, __fmul_rn(w, w));
        }
        part[lane] = r;
    }
    __syncthreads();
    if (lane == 0) {
        n_f[j]  = n;
        t3_f[j] = pairwise_tree(part);
    }
}

// ---------------------------------------------------------------------------
// K2a: x -> bf16 (RN)
__global__ void xcvt_kernel(const float* __restrict__ x, unsigned short* __restrict__ xb) {
    int gid = blockIdx.x * 256 + threadIdx.x;
    float4 v = ((const float4*)x)[gid];
    ushort4 o;
    o.x = f32_to_bf16_rn(v.x); o.y = f32_to_bf16_rn(v.y);
    o.z = f32_to_bf16_rn(v.z); o.w = f32_to_bf16_rn(v.w);
    ((ushort4*)xb)[gid] = o;
}

// K2b: w_hat = e/n (f32, np-exact) -> f32 (refine) + bf16 (coarse)
__global__ void wcvt_kernel(const float* __restrict__ embed, const float* __restrict__ n_f,
                            float* __restrict__ whf, unsigned short* __restrict__ wb) {
    int gid = blockIdx.x * 256 + threadIdx.x;
    int row = gid >> 7;
    float n = n_f[row];
    float4 e = ((const float4*)embed)[gid];
    float4 w;
    w.x = __fdiv_rn(e.x, n); w.y = __fdiv_rn(e.y, n);
    w.z = __fdiv_rn(e.z, n); w.w = __fdiv_rn(e.w, n);
    ((float4*)whf)[gid] = w;
    ushort4 o;
    o.x = f32_to_bf16_rn(w.x); o.y = f32_to_bf16_rn(w.y);
    o.z = f32_to_bf16_rn(w.z); o.w = f32_to_bf16_rn(w.w);
    ((ushort4*)wb)[gid] = o;
}

// ---------------------------------------------------------------------------
__device__ __forceinline__ void top8_insert(float s, int idx, float (&bv)[8], int (&bi)[8]) {
    if (s > bv[7]) {
#pragma unroll
        for (int k = 7; k > 0; --k) {
            bool up = s > bv[k - 1];
            float nv = (s > bv[k]) ? s : bv[k];
            int   ni = (s > bv[k]) ? idx : bi[k];
            bv[k] = up ? bv[k - 1] : nv;
            bi[k] = up ? bi[k - 1] : ni;
        }
        bool up0 = s > bv[0];
        bi[0] = up0 ? idx : bi[0];
        bv[0] = up0 ? s : bv[0];
    }
}

// ---------------------------------------------------------------------------
// K3: bf16 MFMA coarse scoring + fused per-token top-8 over one N-half.
// Grid: (N_TOK/64)*2 blocks; block b: tokens (b>>1)*64, codes (b&1)*2048..+2048.
// 4 waves; wave w computes the 64x64 strip at cols nt*256 + w*64.
//
// R3: counted-vmcnt double-buffer pipeline with scheduler-proof barriers.
// Each STAGE issues exactly 10 global_load_lds per wave; at the publish
// barrier, vmcnt(10) guarantees tile kc landed while tile kc+1's loads stay
// in flight. All barriers explicitly drain the wave's own LDS ops (lgkmcnt 0)
// and are fenced with sched_barrier(0) so no MFMA/VALU/ds op can migrate
// across (the R2 race). The (nt+1,0) prefetch rides through selection.
__global__ __launch_bounds__(256, 2) void coarse_kernel(
        const unsigned short* __restrict__ xb,
        const unsigned short* __restrict__ wb,
        float2* __restrict__ candp) {
    __shared__ __attribute__((aligned(16))) char smem[2 * BUFSZ];

    const int tid  = threadIdx.x;
    const int w    = tid >> 6;         // wave id 0..3
    const int l    = tid & 63;
    const int m0   = (blockIdx.x >> 1) * CBM;
    const int half = blockIdx.x & 1;
    const int n0   = half * NHALF;

    const int srow   = l >> 3;               // row within an 8-row staging group
    const int schunk = (l & 7) ^ srow;       // XOR-swizzled source 16B-chunk
    const int mrow   = l & 15;
    const int kq     = l >> 4;               // 0..3
    const int sw     = mrow & 7;

    // per-lane LDS frag-read byte offsets within a buffer.
    const int aoff0 = mrow * 128 + (kq        ^ sw) * 16;
    const int aoff1 = mrow * 128 + ((kq ^ 4)  ^ sw) * 16;
    const int boff0 = 8192 + w * 8192 + mrow * 128 + (kq       ^ sw) * 16;
    const int boff1 = 8192 + w * 8192 + mrow * 128 + ((kq ^ 4) ^ sw) * 16;

    // per-lane global staging sources (advance gB once per nt)
    const unsigned short* gA0 = xb + (size_t)(m0 + w * 16 +     srow) * DIM + schunk * 8;
    const unsigned short* gA1 = xb + (size_t)(m0 + w * 16 + 8 + srow) * DIM + schunk * 8;
    const unsigned short* gB[8];
#pragma unroll
    for (int c = 0; c < 8; ++c)
        gB[c] = wb + (size_t)(n0 + w * 64 + c * 8 + srow) * DIM + schunk * 8;

    // wave-uniform LDS staging destinations (byte offsets within a buffer)
    const int dA = w * 2048;                 // A rows [w*16, w*16+16)
    const int dB = 8192 + w * 8192;          // B rows [w*64, w*64+64)

    auto STAGE = [&](int dstbuf, int koff) {  // koff in bf16 elements
        char* db = smem + dstbuf * BUFSZ;
        __builtin_amdgcn_global_load_lds(
            (const __attribute__((address_space(1))) void*)(gA0 + koff),
            (__attribute__((address_space(3))) void*)(db + dA), 16, 0, 0);
        __builtin_amdgcn_global_load_lds(
            (const __attribute__((address_space(1))) void*)(gA1 + koff),
            (__attribute__((address_space(3))) void*)(db + dA + 1024), 16, 0, 0);
#pragma unroll
        for (int c = 0; c < 8; ++c)
            __builtin_amdgcn_global_load_lds(
                (const __attribute__((address_space(1))) void*)(gB[c] + koff),
                (__attribute__((address_space(3))) void*)(db + dB + c * 1024), 16, 0, 0);
    };

    // strips in buf1 region; per-thread pointers fixed for the whole kernel
    float* const sS  = (float*)(smem + BUFSZ);
    float* const swp = sS + w * (64 * SPITCH) + kq * (4 * SPITCH) + mrow;
    const float4* const srp = (const float4*)(sS + (tid >> 6) * (64 * SPITCH) + (tid & 63) * SPITCH);

    float bv[8]; int bi[8];
#pragma unroll
    for (int k = 0; k < 8; ++k) { bv[k] = -1e30f; bi[k] = k; }

    // prologue: stage tile (0,0) into buf0
    STAGE(0, 0);

    for (int nt = 0; nt < NT_STEPS; ++nt) {
        f32x4 acc[4][4];
#pragma unroll
        for (int i = 0; i < 4; ++i)
#pragma unroll
            for (int j = 0; j < 4; ++j) acc[i][j] = {0.0f, 0.0f, 0.0f, 0.0f};

#pragma unroll
        for (int kc = 0; kc < KC_STEPS; ++kc) {
            // top barrier: stage target buf[(kc+1)&1] free of readers (WAR).
            // kc==0: covered by selection's closing BARL (or untouched, nt=0).
            if (kc > 0) BARL();

            // prefetch next tile into the other buffer (issue only; no drain)
            if (kc < KC_STEPS - 1) {
                STAGE((kc + 1) & 1, (kc + 1) * CBK);
                BAR_PUB10();           // tile kc landed; tile kc+1 in flight
            } else if (nt < NT_STEPS - 1) {
#pragma unroll
                for (int c = 0; c < 8; ++c) gB[c] += (size_t)CBN * DIM;
                STAGE(0, 0);
                BAR_PUB10();           // prefetch (nt+1,0) rides through selection
            } else {
                BAR_PUB0();            // final tile: nothing left in flight
            }

            const int bb = (kc & 1) * BUFSZ;
            bf16x8 a0[4], b0[4], a1[4], b1[4];
#pragma unroll
            for (int i = 0; i < 4; ++i)
                a0[i] = *(const bf16x8*)(smem + bb + aoff0 + i * 2048);
#pragma unroll
            for (int j = 0; j < 4; ++j)
                b0[j] = *(const bf16x8*)(smem + bb + boff0 + j * 2048);
#pragma unroll
            for (int i = 0; i < 4; ++i)
#pragma unroll
                for (int j = 0; j < 4; ++j)
                    acc[i][j] = __builtin_amdgcn_mfma_f32_16x16x32_bf16(
                        a0[i], b0[j], acc[i][j], 0, 0, 0);
#pragma unroll
            for (int i = 0; i < 4; ++i)
                a1[i] = *(const bf16x8*)(smem + bb + aoff1 + i * 2048);
#pragma unroll
            for (int j = 0; j < 4; ++j)
                b1[j] = *(const bf16x8*)(smem + bb + boff1 + j * 2048);
#pragma unroll
            for (int i = 0; i < 4; ++i)
#pragma unroll
                for (int j = 0; j < 4; ++j)
                    acc[i][j] = __builtin_amdgcn_mfma_f32_16x16x32_bf16(
                        a1[i], b1[j], acc[i][j], 0, 0, 0);
            // BARL at next iteration's top drains these ds_reads explicitly
            // before any wave may overwrite buf[kc&1].
        }

        // selection: 2 half-strip rounds (32 cols each); strips live in buf1
        // region (tile (nt,7) consumed from buf1; the live prefetched tile
        // (nt+1,0) sits in buf0, untouched). The in-flight prefetch is NOT
        // drained here -- its latency hides under selection.
        BARL();   // all waves' buf1 frag reads drained -> strip writes safe
#pragma unroll
        for (int h = 0; h < 2; ++h) {
#pragma unroll
            for (int i = 0; i < 4; ++i)
#pragma unroll
                for (int jj = 0; jj < 2; ++jj) {
                    const int j = h * 2 + jj;
#pragma unroll
                    for (int r = 0; r < 4; ++r)
                        swp[(i * 16 + r) * SPITCH + jj * 16] = acc[i][j][r];
                }
            BARL();   // strip writes drained + visible to scanning threads
            // scan: thread (tok = tid&63, qq = tid>>6) scans strip qq's 32 cols
            int ib = n0 + nt * CBN + (tid >> 6) * 64 + h * 32;
#pragma unroll
            for (int c4 = 0; c4 < 8; ++c4) {
                float4 v = srp[c4];
                float m = fmaxf(fmaxf(v.x, v.y), fmaxf(v.z, v.w));
                if (m > bv[7]) {          // rare: divergent branch into insertion
                    top8_insert(v.x, ib + c4 * 4 + 0, bv, bi);
                    top8_insert(v.y, ib + c4 * 4 + 1, bv, bi);
                    top8_insert(v.z, ib + c4 * 4 + 2, bv, bi);
                    top8_insert(v.w, ib + c4 * 4 + 3, bv, bi);
                }
            }
            BARL();   // scan reads drained before strips overwritten / restaged
        }
    }

    // merge the 4 col-quarter top-8 lists per token; emit (score, idx) pairs.
    // buf0 region is dead now (last tile consumed; no prefetch outstanding).
    float* mv = (float*)smem;              // [64][32]
    int*   mi = (int*)(smem + 8192);       // [64][32]
    {
        int tok = tid & 63, qq = tid >> 6;
#pragma unroll
        for (int k = 0; k < 8; ++k) {
            mv[tok * 32 + qq * 8 + k] = bv[k];
            mi[tok * 32 + qq * 8 + k] = bi[k];
        }
    }
    BARL();
    if (tid < 64) {
        float fv[8]; int fi[8];
#pragma unroll
        for (int k = 0; k < 8; ++k) { fv[k] = -1e30f; fi[k] = k; }
        for (int t = 0; t < 32; ++t) top8_insert(mv[tid * 32 + t], mi[tid * 32 + t], fv, fi);
        float2* cp = candp + ((size_t)(m0 + tid) * 2 + half) * 8;
#pragma unroll
        for (int k = 0; k < 8; ++k) cp[k] = make_float2(fv[k], __int_as_float(fi[k]));
    }
}

// ---------------------------------------------------------------------------
// K3b: merge the two halves' top-8 lists -> final 8 candidate indices/token.
__global__ void merge_kernel(const float2* __restrict__ candp, int* __restrict__ cand8) {
    int tok = blockIdx.x * 256 + threadIdx.x;
    float bv[8]; int bi[8];
#pragma unroll
    for (int k = 0; k < 8; ++k) { bv[k] = -1e30f; bi[k] = k; }
    const float2* cp = candp + (size_t)tok * 16;
#pragma unroll
    for (int t = 0; t < 16; ++t) {
        float2 p = cp[t];
        top8_insert(p.x, __float_as_int(p.y), bv, bi);
    }
    int* o = cand8 + (size_t)tok * 8;
#pragma unroll
    for (int k = 0; k < 8; ++k) o[k] = bi[k];
}

// ---------------------------------------------------------------------------
// K4: f32-replicated dist over 8 candidates (np-exact), gather + MSE partial.
__global__ void refine_kernel(const float* __restrict__ x,
                              const float* __restrict__ embed,
                              const float* __restrict__ whf,
                              const float* __restrict__ t3_f,
                              const int* __restrict__ cand,
                              float* __restrict__ out,
                              double* __restrict__ partial) {
    __shared__ float part[4][32];
    __shared__ double wsum[4];
    const int wid  = threadIdx.x >> 6;
    const int lane = threadIdx.x & 63;
    const int tok  = blockIdx.x * 4 + wid;
    const float* f = x + (size_t)tok * DIM;

    if (lane < 32) {
        int base = (lane >> 3) * 128 + (lane & 7);
        float v = f[base];
        float r = __fmul_rn(v, v);
#pragma unroll
        for (int i = 1; i < 16; ++i) {
            float u = f[base + 8 * i];
            r = __fadd_rn(r, __fmul_rn(u, u));
        }
        part[wid][lane] = r;
    }
    __syncthreads();
    float t1 = pairwise_tree(part[wid]);

    float4 f0 = *(const float4*)(f + lane * 8);
    float4 f1 = *(const float4*)(f + lane * 8 + 4);

    float bd = 1e30f; int bc = 0x7fffffff;
    const int* cp = cand + (size_t)tok * 8;
#pragma unroll
    for (int k = 0; k < 8; ++k) {
        int c = cp[k];
        const float* wh = whf + (size_t)c * DIM + lane * 8;
        float4 w0 = *(const float4*)wh;
        float4 w1 = *(const float4*)(wh + 4);
        double s = (double)f0.x * w0.x + (double)f0.y * w0.y
                 + (double)f0.z * w0.z + (double)f0.w * w0.w
                 + (double)f1.x * w1.x + (double)f1.y * w1.y
                 + (double)f1.z * w1.z + (double)f1.w * w1.w;
#pragma unroll
        for (int off = 32; off > 0; off >>= 1) s += __shfl_xor(s, off);
        float mm = (float)s;
        float dist = __fadd_rn(__fsub_rn(t1, __fmul_rn(2.0f, mm)), t3_f[c]);
        if (dist < bd || (dist == bd && c < bc)) { bd = dist; bc = c; }
    }

    const float* eb = embed + (size_t)bc * DIM;
    double dsum = 0.0;
#pragma unroll
    for (int r = 0; r < DIM / 64; ++r) {
        int d = lane + 64 * r;
        float q = eb[d];
        out[(size_t)tok * DIM + d] = q;   // (quantize + quantize_1)*0.5 == quantize
        double dd = (double)q - (double)f[d];
        dsum += dd * dd;
    }
#pragma unroll
    for (int off = 32; off > 0; off >>= 1) dsum += __shfl_xor(dsum, off);
    if (lane == 0) wsum[wid] = dsum;
    __syncthreads();
    if (threadIdx.x == 0)
        partial[blockIdx.x] = wsum[0] + wsum[1] + wsum[2] + wsum[3];
}

// ---------------------------------------------------------------------------
__global__ void finalize_kernel(const double* __restrict__ partial,
                                float* __restrict__ out) {
    __shared__ double acc[4];
    int tid = threadIdx.x;
    double s = 0.0;
    for (int i = tid; i < N_TOK / 4; i += 256) s += partial[i];
#pragma unroll
    for (int off = 32; off > 0; off >>= 1) s += __shfl_xor(s, off);
    if ((tid & 63) == 0) acc[tid >> 6] = s;
    __syncthreads();
    if (tid == 0)
        out[(size_t)N_TOK * DIM] =
            (float)((acc[0] + acc[1] + acc[2] + acc[3]) * (1.0 / ((double)N_TOK * DIM)));
}

// ---------------------------------------------------------------------------
extern "C" void kernel_launch(void* const* d_in, const int* in_sizes, int n_in,
                              void* d_out, int out_size, void* d_ws, size_t ws_size,
                              hipStream_t stream) {
    const float* x     = (const float*)d_in[0];   // [32768, 512]
    const float* embed = (const float*)d_in[1];   // [4096, 512]
    float* out = (float*)d_out;                   // 16777216 + 1 floats

    char* wsb = (char*)d_ws;
    size_t off = 0;
    double* partial = (double*)(wsb + off); off += 65536;            // 8192 f64
    float*  n_f     = (float*) (wsb + off); off += 16384;
    float*  t3_f    = (float*) (wsb + off); off += 16384;
    float2* candp   = (float2*)(wsb + off); off += (size_t)N_TOK * 16 * 8;  // 4 MB
    int*    cand8   = (int*)   (wsb + off); off += (size_t)N_TOK * 8 * 4;   // 1 MB
    unsigned short* xb = (unsigned short*)(wsb + off); off += (size_t)N_TOK * DIM * 2;  // 32 MB
    unsigned short* wb = (unsigned short*)(wsb + off); off += (size_t)N_CODE * DIM * 2; // 4 MB
    float*  whf     = (float*) (wsb + off);                                  // 8 MB

    xcvt_kernel    <<<16384, 256, 0, stream>>>(x, xb);
    norms_kernel   <<<N_CODE, 64, 0, stream>>>(embed, n_f, t3_f);
    wcvt_kernel    <<<2048, 256, 0, stream>>>(embed, n_f, whf, wb);
    coarse_kernel  <<<(N_TOK / CBM) * 2, 256, 0, stream>>>(xb, wb, candp);
    merge_kernel   <<<N_TOK / 256, 256, 0, stream>>>(candp, cand8);
    refine_kernel  <<<N_TOK / 4, 256, 0, stream>>>(x, embed, whf, t3_f, cand8, out, partial);
    finalize_kernel<<<1, 256, 0, stream>>>(partial, out);
}

// Round 4
// 443.115 us; speedup vs baseline: 1.2447x; 1.2447x over previous
//
#include <hip/hip_runtime.h>
#include <math.h>

// Problem constants (B=16, T=2048, DIM=512, N_EMBED=4096)
#define N_TOK   32768
#define N_CODE  4096
#define DIM     512

// Coarse MFMA tiling: block = 64 tokens x 2048 codes (one N-half)
#define CBM 64
#define NHALF 2048
#define CBN 256                   // codes per nt step
#define CBK 64                    // K chunk per staging round
#define NT_STEPS (NHALF / CBN)    // 8
#define KC_STEPS (DIM / CBK)      // 8
#define SPITCH 36                 // score strip pitch (u32), 16B aligned
#define BUFSZ 40960               // one LDS tile buffer: A 8KB + B 32KB

// ---------------------------------------------------------------------------
// Scheduler-movement-proof sync points (rule #18: register-only MFMA/VALU can
// cross inline asm despite "memory" clobber, dragging the compiler's lgkmcnt
// waits with them => a wave can pass a raw s_barrier with ds ops outstanding.
// Fix: sched_barrier(0) fences on both sides + explicit lgkmcnt drain).
#define SFENCE() __builtin_amdgcn_sched_barrier(0)

// drain own LDS ops, then barrier (WAR protection / LDS publish)
#define BARL() do { \
    SFENCE(); \
    asm volatile("s_waitcnt lgkmcnt(0)" ::: "memory"); \
    __builtin_amdgcn_s_barrier(); \
    SFENCE(); \
} while (0)

// publish staged tile: 10 newest vmem ops (next tile's DMA) stay in flight
#define BAR_PUB10() do { \
    SFENCE(); \
    asm volatile("s_waitcnt vmcnt(10)" ::: "memory"); \
    __builtin_amdgcn_s_barrier(); \
    SFENCE(); \
} while (0)

// publish final tile: nothing left in flight
#define BAR_PUB0() do { \
    SFENCE(); \
    asm volatile("s_waitcnt vmcnt(0)" ::: "memory"); \
    __builtin_amdgcn_s_barrier(); \
    SFENCE(); \
} while (0)

typedef __bf16 bf16x8 __attribute__((ext_vector_type(8)));
typedef float  f32x4  __attribute__((ext_vector_type(4)));

__device__ __forceinline__ unsigned short f32_to_bf16_rn(float f) {
    union { float f; unsigned int u; } c; c.f = f;
    unsigned int u = c.u;
    return (unsigned short)((u + 0x7FFFu + ((u >> 16) & 1u)) >> 16);
}

// monotone f32 -> sortable u32 (increasing)
__device__ __forceinline__ unsigned f32_sortkey(float f) {
    unsigned u = __float_as_uint(f);
    return u ^ ((unsigned)(((int)u) >> 31) | 0x80000000u);
}

// ---------------------------------------------------------------------------
// Branchless top-8 over packed u32 keys (value in high 20 bits, inverted idx
// in low 12). 3 VALU per step: v_cmp + v_max_u32 + v_cndmask.
__device__ __forceinline__ void top8k_insert(unsigned s, unsigned (&bv)[8]) {
#pragma unroll
    for (int k = 7; k > 0; --k) {
        unsigned t = bv[k] > s ? bv[k] : s;          // v_max_u32
        bv[k] = (s > bv[k - 1]) ? bv[k - 1] : t;     // v_cmp + v_cndmask
    }
    bv[0] = bv[0] > s ? bv[0] : s;
}

// ---------------------------------------------------------------------------
// numpy pairwise f32 sum over 512 contiguous elements (bit-exact).
__device__ __forceinline__ float pairwise_tree(const float* p) {
    float P[4];
#pragma unroll
    for (int b = 0; b < 4; ++b) {
        float t01 = __fadd_rn(p[b * 8 + 0], p[b * 8 + 1]);
        float t23 = __fadd_rn(p[b * 8 + 2], p[b * 8 + 3]);
        float t45 = __fadd_rn(p[b * 8 + 4], p[b * 8 + 5]);
        float t67 = __fadd_rn(p[b * 8 + 6], p[b * 8 + 7]);
        P[b] = __fadd_rn(__fadd_rn(t01, t23), __fadd_rn(t45, t67));
    }
    return __fadd_rn(__fadd_rn(P[0], P[1]), __fadd_rn(P[2], P[3]));
}

// ---------------------------------------------------------------------------
// K1: per-code f32-replicated norm + t3.
__global__ void norms_kernel(const float* __restrict__ embed,
                             float* __restrict__ n_f,
                             float* __restrict__ t3_f) {
    __shared__ float part[32];
    int j = blockIdx.x;
    int lane = threadIdx.x;
    const float* e = embed + (size_t)j * DIM;

    if (lane < 32) {
        int base = (lane >> 3) * 128 + (lane & 7);
        float v = e[base];
        float r = __fmul_rn(v, v);
#pragma unroll
        for (int i = 1; i < 16; ++i) {
            float u = e[base + 8 * i];
            r = __fadd_rn(r, __fmul_rn(u, u));
        }
        part[lane] = r;
    }
    __syncthreads();
    float S = pairwise_tree(part);
    float n = __fsqrt_rn(S);
    __syncthreads();

    if (lane < 32) {
        int base = (lane >> 3) * 128 + (lane & 7);
        float w0 = __fdiv_rn(e[base], n);
        float r = __fmul_rn(w0, w0);
#pragma unroll
        for (int i = 1; i < 16; ++i) {
            float w = __fdiv_rn(e[base + 8 * i], n);
            r = __fadd_rn(r, __fmul_rn(w, w));
        }
        part[lane] = r;
    }
    __syncthreads();
    if (lane == 0) {
        n_f[j]  = n;
        t3_f[j] = pairwise_tree(part);
    }
}

// ---------------------------------------------------------------------------
// K2a: x -> bf16 (RN)
__global__ void xcvt_kernel(const float* __restrict__ x, unsigned short* __restrict__ xb) {
    int gid = blockIdx.x * 256 + threadIdx.x;
    float4 v = ((const float4*)x)[gid];
    ushort4 o;
    o.x = f32_to_bf16_rn(v.x); o.y = f32_to_bf16_rn(v.y);
    o.z = f32_to_bf16_rn(v.z); o.w = f32_to_bf16_rn(v.w);
    ((ushort4*)xb)[gid] = o;
}

// K2b: w_hat = e/n (f32, np-exact) -> f32 (refine) + bf16 (coarse)
__global__ void wcvt_kernel(const float* __restrict__ embed, const float* __restrict__ n_f,
                            float* __restrict__ whf, unsigned short* __restrict__ wb) {
    int gid = blockIdx.x * 256 + threadIdx.x;
    int row = gid >> 7;
    float n = n_f[row];
    float4 e = ((const float4*)embed)[gid];
    float4 w;
    w.x = __fdiv_rn(e.x, n); w.y = __fdiv_rn(e.y, n);
    w.z = __fdiv_rn(e.z, n); w.w = __fdiv_rn(e.w, n);
    ((float4*)whf)[gid] = w;
    ushort4 o;
    o.x = f32_to_bf16_rn(w.x); o.y = f32_to_bf16_rn(w.y);
    o.z = f32_to_bf16_rn(w.z); o.w = f32_to_bf16_rn(w.w);
    ((ushort4*)wb)[gid] = o;
}

// ---------------------------------------------------------------------------
// K3: bf16 MFMA coarse scoring + fused per-token top-8 over one N-half.
// Grid: (N_TOK/64)*2 blocks; block b: tokens (b>>1)*64, codes (b&1)*2048..+2048.
// 4 waves; wave w computes the 64x64 strip at cols nt*256 + w*64.
//
// R4: selection is the VALU bottleneck (R3 analysis: the "rare" insert branch
// is taken ~100% of the time at wave level). Scores are packed at strip-write
// time into sortable u32 keys: [monotone f32 top 20 bits | (4095 - code_idx)].
// 20-bit score = sign+exp+11 mantissa bits; top-8 gaps (~0.4) >> quantization
// granularity (~3e-3), and the inverted idx preserves the reference's
// smallest-index tie-break. Scan = branchless 3-VALU/step top-8 over u32.
// Barrier skeleton identical to R3 (verified correct).
__global__ __launch_bounds__(256, 2) void coarse_kernel(
        const unsigned short* __restrict__ xb,
        const unsigned short* __restrict__ wb,
        unsigned* __restrict__ candp) {
    __shared__ __attribute__((aligned(16))) char smem[2 * BUFSZ];

    const int tid  = threadIdx.x;
    const int w    = tid >> 6;         // wave id 0..3
    const int l    = tid & 63;
    const int m0   = (blockIdx.x >> 1) * CBM;
    const int half = blockIdx.x & 1;
    const int n0   = half * NHALF;

    const int srow   = l >> 3;               // row within an 8-row staging group
    const int schunk = (l & 7) ^ srow;       // XOR-swizzled source 16B-chunk
    const int mrow   = l & 15;
    const int kq     = l >> 4;               // 0..3
    const int sw     = mrow & 7;

    // per-lane LDS frag-read byte offsets within a buffer.
    const int aoff0 = mrow * 128 + (kq        ^ sw) * 16;
    const int aoff1 = mrow * 128 + ((kq ^ 4)  ^ sw) * 16;
    const int boff0 = 8192 + w * 8192 + mrow * 128 + (kq       ^ sw) * 16;
    const int boff1 = 8192 + w * 8192 + mrow * 128 + ((kq ^ 4) ^ sw) * 16;

    // per-lane global staging sources (advance gB once per nt)
    const unsigned short* gA0 = xb + (size_t)(m0 + w * 16 +     srow) * DIM + schunk * 8;
    const unsigned short* gA1 = xb + (size_t)(m0 + w * 16 + 8 + srow) * DIM + schunk * 8;
    const unsigned short* gB[8];
#pragma unroll
    for (int c = 0; c < 8; ++c)
        gB[c] = wb + (size_t)(n0 + w * 64 + c * 8 + srow) * DIM + schunk * 8;

    // wave-uniform LDS staging destinations (byte offsets within a buffer)
    const int dA = w * 2048;                 // A rows [w*16, w*16+16)
    const int dB = 8192 + w * 8192;          // B rows [w*64, w*64+64)

    auto STAGE = [&](int dstbuf, int koff) {  // koff in bf16 elements
        char* db = smem + dstbuf * BUFSZ;
        __builtin_amdgcn_global_load_lds(
            (const __attribute__((address_space(1))) void*)(gA0 + koff),
            (__attribute__((address_space(3))) void*)(db + dA), 16, 0, 0);
        __builtin_amdgcn_global_load_lds(
            (const __attribute__((address_space(1))) void*)(gA1 + koff),
            (__attribute__((address_space(3))) void*)(db + dA + 1024), 16, 0, 0);
#pragma unroll
        for (int c = 0; c < 8; ++c)
            __builtin_amdgcn_global_load_lds(
                (const __attribute__((address_space(1))) void*)(gB[c] + koff),
                (__attribute__((address_space(3))) void*)(db + dB + c * 1024), 16, 0, 0);
    };

    // strips (packed u32 keys) in buf1 region; fixed per-thread pointers
    unsigned* const sS  = (unsigned*)(smem + BUFSZ);
    unsigned* const swp = sS + w * (64 * SPITCH) + kq * (4 * SPITCH) + mrow;
    const uint4* const srp = (const uint4*)(sS + (tid >> 6) * (64 * SPITCH) + (tid & 63) * SPITCH);

    // inverted-index base for key packing: idx_field = invb - nt*256 - h*32 - jj*16
    const int invb = 4095 - n0 - w * 64 - mrow;

    unsigned bv[8];
#pragma unroll
    for (int k = 0; k < 8; ++k) bv[k] = 0u;

    // prologue: stage tile (0,0) into buf0
    STAGE(0, 0);

    for (int nt = 0; nt < NT_STEPS; ++nt) {
        f32x4 acc[4][4];
#pragma unroll
        for (int i = 0; i < 4; ++i)
#pragma unroll
            for (int j = 0; j < 4; ++j) acc[i][j] = {0.0f, 0.0f, 0.0f, 0.0f};

#pragma unroll
        for (int kc = 0; kc < KC_STEPS; ++kc) {
            // top barrier: stage target buf[(kc+1)&1] free of readers (WAR).
            // kc==0: covered by selection's closing BARL (or untouched, nt=0).
            if (kc > 0) BARL();

            // prefetch next tile into the other buffer (issue only; no drain)
            if (kc < KC_STEPS - 1) {
                STAGE((kc + 1) & 1, (kc + 1) * CBK);
                BAR_PUB10();           // tile kc landed; tile kc+1 in flight
            } else if (nt < NT_STEPS - 1) {
#pragma unroll
                for (int c = 0; c < 8; ++c) gB[c] += (size_t)CBN * DIM;
                STAGE(0, 0);
                BAR_PUB10();           // prefetch (nt+1,0) rides through selection
            } else {
                BAR_PUB0();            // final tile: nothing left in flight
            }

            const int bb = (kc & 1) * BUFSZ;
            bf16x8 a0[4], b0[4], a1[4], b1[4];
#pragma unroll
            for (int i = 0; i < 4; ++i)
                a0[i] = *(const bf16x8*)(smem + bb + aoff0 + i * 2048);
#pragma unroll
            for (int j = 0; j < 4; ++j)
                b0[j] = *(const bf16x8*)(smem + bb + boff0 + j * 2048);
#pragma unroll
            for (int i = 0; i < 4; ++i)
#pragma unroll
                for (int j = 0; j < 4; ++j)
                    acc[i][j] = __builtin_amdgcn_mfma_f32_16x16x32_bf16(
                        a0[i], b0[j], acc[i][j], 0, 0, 0);
#pragma unroll
            for (int i = 0; i < 4; ++i)
                a1[i] = *(const bf16x8*)(smem + bb + aoff1 + i * 2048);
#pragma unroll
            for (int j = 0; j < 4; ++j)
                b1[j] = *(const bf16x8*)(smem + bb + boff1 + j * 2048);
#pragma unroll
            for (int i = 0; i < 4; ++i)
#pragma unroll
                for (int j = 0; j < 4; ++j)
                    acc[i][j] = __builtin_amdgcn_mfma_f32_16x16x32_bf16(
                        a1[i], b1[j], acc[i][j], 0, 0, 0);
            // BARL at next iteration's top drains these ds_reads explicitly
            // before any wave may overwrite buf[kc&1].
        }

        // selection: 2 half-strip rounds (32 cols each); strips live in buf1
        // region (tile (nt,7) consumed from buf1; the live prefetched tile
        // (nt+1,0) sits in buf0, untouched). The in-flight prefetch is NOT
        // drained here -- its latency hides under selection.
        BARL();   // all waves' buf1 frag reads drained -> strip writes safe
#pragma unroll
        for (int h = 0; h < 2; ++h) {
#pragma unroll
            for (int i = 0; i < 4; ++i)
#pragma unroll
                for (int jj = 0; jj < 2; ++jj) {
                    const int j = h * 2 + jj;
                    const unsigned ifld = (unsigned)(invb - (nt * 256 + h * 32 + jj * 16));
#pragma unroll
                    for (int r = 0; r < 4; ++r) {
                        unsigned key = (f32_sortkey(acc[i][j][r]) & 0xFFFFF000u) | ifld;
                        swp[(i * 16 + r) * SPITCH + jj * 16] = key;
                    }
                }
            BARL();   // strip writes drained + visible to scanning threads
            // scan: thread (tok = tid&63, qq = tid>>6) scans strip qq's 32
            // packed keys, fully branchless (idx embedded in the key).
#pragma unroll
            for (int c4 = 0; c4 < 8; ++c4) {
                uint4 v = srp[c4];
                top8k_insert(v.x, bv);
                top8k_insert(v.y, bv);
                top8k_insert(v.z, bv);
                top8k_insert(v.w, bv);
            }
            BARL();   // scan reads drained before strips overwritten / restaged
        }
    }

    // merge the 4 col-quarter top-8 lists per token; emit packed keys.
    // buf0 region is dead now (last tile consumed; no prefetch outstanding).
    unsigned* mk = (unsigned*)smem;        // [64][32] u32 keys
    {
        int tok = tid & 63, qq = tid >> 6;
#pragma unroll
        for (int k = 0; k < 8; ++k) mk[tok * 32 + qq * 8 + k] = bv[k];
    }
    BARL();
    if (tid < 64) {
        unsigned fv[8];
#pragma unroll
        for (int k = 0; k < 8; ++k) fv[k] = 0u;
        for (int t = 0; t < 32; ++t) top8k_insert(mk[tid * 32 + t], fv);
        unsigned* cp = candp + ((size_t)(m0 + tid) * 2 + half) * 8;
#pragma unroll
        for (int k = 0; k < 8; ++k) cp[k] = fv[k];
    }
}

// ---------------------------------------------------------------------------
// K3b: merge the two halves' top-8 key lists -> final 8 candidate idx/token.
__global__ void merge_kernel(const unsigned* __restrict__ candp, int* __restrict__ cand8) {
    int tok = blockIdx.x * 256 + threadIdx.x;
    unsigned bv[8];
#pragma unroll
    for (int k = 0; k < 8; ++k) bv[k] = 0u;
    const unsigned* cp = candp + (size_t)tok * 16;
#pragma unroll
    for (int t = 0; t < 16; ++t) top8k_insert(cp[t], bv);
    int* o = cand8 + (size_t)tok * 8;
#pragma unroll
    for (int k = 0; k < 8; ++k) o[k] = 4095 - (int)(bv[k] & 0xFFFu);
}

// ---------------------------------------------------------------------------
// K4: f32-replicated dist over 8 candidates (np-exact), gather + MSE partial.
__global__ void refine_kernel(const float* __restrict__ x,
                              const float* __restrict__ embed,
                              const float* __restrict__ whf,
                              const float* __restrict__ t3_f,
                              const int* __restrict__ cand,
                              float* __restrict__ out,
                              double* __restrict__ partial) {
    __shared__ float part[4][32];
    __shared__ double wsum[4];
    const int wid  = threadIdx.x >> 6;
    const int lane = threadIdx.x & 63;
    const int tok  = blockIdx.x * 4 + wid;
    const float* f = x + (size_t)tok * DIM;

    if (lane < 32) {
        int base = (lane >> 3) * 128 + (lane & 7);
        float v = f[base];
        float r = __fmul_rn(v, v);
#pragma unroll
        for (int i = 1; i < 16; ++i) {
            float u = f[base + 8 * i];
            r = __fadd_rn(r, __fmul_rn(u, u));
        }
        part[wid][lane] = r;
    }
    __syncthreads();
    float t1 = pairwise_tree(part[wid]);

    float4 f0 = *(const float4*)(f + lane * 8);
    float4 f1 = *(const float4*)(f + lane * 8 + 4);

    float bd = 1e30f; int bc = 0x7fffffff;
    const int* cp = cand + (size_t)tok * 8;
#pragma unroll
    for (int k = 0; k < 8; ++k) {
        int c = cp[k];
        const float* wh = whf + (size_t)c * DIM + lane * 8;
        float4 w0 = *(const float4*)wh;
        float4 w1 = *(const float4*)(wh + 4);
        double s = (double)f0.x * w0.x + (double)f0.y * w0.y
                 + (double)f0.z * w0.z + (double)f0.w * w0.w
                 + (double)f1.x * w1.x + (double)f1.y * w1.y
                 + (double)f1.z * w1.z + (double)f1.w * w1.w;
#pragma unroll
        for (int off = 32; off > 0; off >>= 1) s += __shfl_xor(s, off);
        float mm = (float)s;
        float dist = __fadd_rn(__fsub_rn(t1, __fmul_rn(2.0f, mm)), t3_f[c]);
        if (dist < bd || (dist == bd && c < bc)) { bd = dist; bc = c; }
    }

    const float* eb = embed + (size_t)bc * DIM;
    double dsum = 0.0;
#pragma unroll
    for (int r = 0; r < DIM / 64; ++r) {
        int d = lane + 64 * r;
        float q = eb[d];
        out[(size_t)tok * DIM + d] = q;   // (quantize + quantize_1)*0.5 == quantize
        double dd = (double)q - (double)f[d];
        dsum += dd * dd;
    }
#pragma unroll
    for (int off = 32; off > 0; off >>= 1) dsum += __shfl_xor(dsum, off);
    if (lane == 0) wsum[wid] = dsum;
    __syncthreads();
    if (threadIdx.x == 0)
        partial[blockIdx.x] = wsum[0] + wsum[1] + wsum[2] + wsum[3];
}

// ---------------------------------------------------------------------------
__global__ void finalize_kernel(const double* __restrict__ partial,
                                float* __restrict__ out) {
    __shared__ double acc[4];
    int tid = threadIdx.x;
    double s = 0.0;
    for (int i = tid; i < N_TOK / 4; i += 256) s += partial[i];
#pragma unroll
    for (int off = 32; off > 0; off >>= 1) s += __shfl_xor(s, off);
    if ((tid & 63) == 0) acc[tid >> 6] = s;
    __syncthreads();
    if (tid == 0)
        out[(size_t)N_TOK * DIM] =
            (float)((acc[0] + acc[1] + acc[2] + acc[3]) * (1.0 / ((double)N_TOK * DIM)));
}

// ---------------------------------------------------------------------------
extern "C" void kernel_launch(void* const* d_in, const int* in_sizes, int n_in,
                              void* d_out, int out_size, void* d_ws, size_t ws_size,
                              hipStream_t stream) {
    const float* x     = (const float*)d_in[0];   // [32768, 512]
    const float* embed = (const float*)d_in[1];   // [4096, 512]
    float* out = (float*)d_out;                   // 16777216 + 1 floats

    char* wsb = (char*)d_ws;
    size_t off = 0;
    double* partial = (double*)(wsb + off); off += 65536;            // 8192 f64
    float*  n_f     = (float*) (wsb + off); off += 16384;
    float*  t3_f    = (float*) (wsb + off); off += 16384;
    unsigned* candp = (unsigned*)(wsb + off); off += (size_t)N_TOK * 16 * 4;  // 2 MB
    int*    cand8   = (int*)   (wsb + off); off += (size_t)N_TOK * 8 * 4;     // 1 MB
    unsigned short* xb = (unsigned short*)(wsb + off); off += (size_t)N_TOK * DIM * 2;  // 32 MB
    unsigned short* wb = (unsigned short*)(wsb + off); off += (size_t)N_CODE * DIM * 2; // 4 MB
    float*  whf     = (float*) (wsb + off);                                   // 8 MB

    xcvt_kernel    <<<16384, 256, 0, stream>>>(x, xb);
    norms_kernel   <<<N_CODE, 64, 0, stream>>>(embed, n_f, t3_f);
    wcvt_kernel    <<<2048, 256, 0, stream>>>(embed, n_f, whf, wb);
    coarse_kernel  <<<(N_TOK / CBM) * 2, 256, 0, stream>>>(xb, wb, candp);
    merge_kernel   <<<N_TOK / 256, 256, 0, stream>>>(candp, cand8);
    refine_kernel  <<<N_TOK / 4, 256, 0, stream>>>(x, embed, whf, t3_f, cand8, out, partial);
    finalize_kernel<<<1, 256, 0, stream>>>(partial, out);
}

// Round 5
// 373.489 us; speedup vs baseline: 1.4767x; 1.1864x over previous
//
#include <hip/hip_runtime.h>
#include <math.h>

// Problem constants (B=16, T=2048, DIM=512, N_EMBED=4096)
#define N_TOK   32768
#define N_CODE  4096
#define DIM     512

// Coarse MFMA tiling: block = 64 tokens x 2048 codes (one N-half)
#define CBM 64
#define NHALF 2048
#define CBN 256                   // codes per nt step
#define CBK 64                    // K chunk per staging round
#define NT_STEPS (NHALF / CBN)    // 8
#define KC_STEPS (DIM / CBK)      // 8
#define SPITCH 36                 // score strip pitch (u32), 16B aligned
#define BUFSZ 40960               // one LDS tile buffer: A 8KB + B 32KB

// ---------------------------------------------------------------------------
// Scheduler-movement-proof sync points (rule #18: register-only MFMA/VALU can
// cross inline asm despite "memory" clobber, dragging the compiler's lgkmcnt
// waits with them => a wave can pass a raw s_barrier with ds ops outstanding.
// Fix: sched_barrier(0) fences on both sides + explicit lgkmcnt drain).
#define SFENCE() __builtin_amdgcn_sched_barrier(0)

// drain own LDS ops, then barrier (WAR protection / LDS publish)
#define BARL() do { \
    SFENCE(); \
    asm volatile("s_waitcnt lgkmcnt(0)" ::: "memory"); \
    __builtin_amdgcn_s_barrier(); \
    SFENCE(); \
} while (0)

// publish staged tile: 10 newest vmem ops (next tile's DMA) stay in flight
#define BAR_PUB10() do { \
    SFENCE(); \
    asm volatile("s_waitcnt vmcnt(10)" ::: "memory"); \
    __builtin_amdgcn_s_barrier(); \
    SFENCE(); \
} while (0)

// publish final tile: nothing left in flight
#define BAR_PUB0() do { \
    SFENCE(); \
    asm volatile("s_waitcnt vmcnt(0)" ::: "memory"); \
    __builtin_amdgcn_s_barrier(); \
    SFENCE(); \
} while (0)

typedef __bf16 bf16x8 __attribute__((ext_vector_type(8)));
typedef float  f32x4  __attribute__((ext_vector_type(4)));

__device__ __forceinline__ unsigned short f32_to_bf16_rn(float f) {
    union { float f; unsigned int u; } c; c.f = f;
    unsigned int u = c.u;
    return (unsigned short)((u + 0x7FFFu + ((u >> 16) & 1u)) >> 16);
}

// monotone f32 -> sortable u32 (increasing)
__device__ __forceinline__ unsigned f32_sortkey(float f) {
    unsigned u = __float_as_uint(f);
    return u ^ ((unsigned)(((int)u) >> 31) | 0x80000000u);
}

// ---------------------------------------------------------------------------
// Branchless top-8 over packed u32 keys (used by merge_kernel only).
__device__ __forceinline__ void top8k_insert(unsigned s, unsigned (&bv)[8]) {
#pragma unroll
    for (int k = 7; k > 0; --k) {
        unsigned t = bv[k] > s ? bv[k] : s;          // v_max_u32
        bv[k] = (s > bv[k - 1]) ? bv[k - 1] : t;     // v_cmp + v_cndmask
    }
    bv[0] = bv[0] > s ? bv[0] : s;
}

// Sorted top-3 update, 5 VALU (min/max only), keeps b0>=b1>=b2.
__device__ __forceinline__ void top3k_insert(unsigned s, unsigned &b0,
                                             unsigned &b1, unsigned &b2) {
    unsigned t = b0 < s ? b0 : s;   // min(b0,s)
    b0 = b0 > s ? b0 : s;           // max
    unsigned u = b1 < t ? b1 : t;   // min(b1,t)
    b1 = b1 > t ? b1 : t;           // max
    b2 = b2 > u ? b2 : u;           // max
}

// ---------------------------------------------------------------------------
// numpy pairwise f32 sum over 512 contiguous elements (bit-exact).
__device__ __forceinline__ float pairwise_tree(const float* p) {
    float P[4];
#pragma unroll
    for (int b = 0; b < 4; ++b) {
        float t01 = __fadd_rn(p[b * 8 + 0], p[b * 8 + 1]);
        float t23 = __fadd_rn(p[b * 8 + 2], p[b * 8 + 3]);
        float t45 = __fadd_rn(p[b * 8 + 4], p[b * 8 + 5]);
        float t67 = __fadd_rn(p[b * 8 + 6], p[b * 8 + 7]);
        P[b] = __fadd_rn(__fadd_rn(t01, t23), __fadd_rn(t45, t67));
    }
    return __fadd_rn(__fadd_rn(P[0], P[1]), __fadd_rn(P[2], P[3]));
}

// ---------------------------------------------------------------------------
// K1: per-code f32-replicated norm + t3.
__global__ void norms_kernel(const float* __restrict__ embed,
                             float* __restrict__ n_f,
                             float* __restrict__ t3_f) {
    __shared__ float part[32];
    int j = blockIdx.x;
    int lane = threadIdx.x;
    const float* e = embed + (size_t)j * DIM;

    if (lane < 32) {
        int base = (lane >> 3) * 128 + (lane & 7);
        float v = e[base];
        float r = __fmul_rn(v, v);
#pragma unroll
        for (int i = 1; i < 16; ++i) {
            float u = e[base + 8 * i];
            r = __fadd_rn(r, __fmul_rn(u, u));
        }
        part[lane] = r;
    }
    __syncthreads();
    float S = pairwise_tree(part);
    float n = __fsqrt_rn(S);
    __syncthreads();

    if (lane < 32) {
        int base = (lane >> 3) * 128 + (lane & 7);
        float w0 = __fdiv_rn(e[base], n);
        float r = __fmul_rn(w0, w0);
#pragma unroll
        for (int i = 1; i < 16; ++i) {
            float w = __fdiv_rn(e[base + 8 * i], n);
            r = __fadd_rn(r, __fmul_rn(w, w));
        }
        part[lane] = r;
    }
    __syncthreads();
    if (lane == 0) {
        n_f[j]  = n;
        t3_f[j] = pairwise_tree(part);
    }
}

// ---------------------------------------------------------------------------
// K2a: x -> bf16 (RN)
__global__ void xcvt_kernel(const float* __restrict__ x, unsigned short* __restrict__ xb) {
    int gid = blockIdx.x * 256 + threadIdx.x;
    float4 v = ((const float4*)x)[gid];
    ushort4 o;
    o.x = f32_to_bf16_rn(v.x); o.y = f32_to_bf16_rn(v.y);
    o.z = f32_to_bf16_rn(v.z); o.w = f32_to_bf16_rn(v.w);
    ((ushort4*)xb)[gid] = o;
}

// K2b: w_hat = e/n (f32, np-exact) -> f32 (refine) + bf16 (coarse)
__global__ void wcvt_kernel(const float* __restrict__ embed, const float* __restrict__ n_f,
                            float* __restrict__ whf, unsigned short* __restrict__ wb) {
    int gid = blockIdx.x * 256 + threadIdx.x;
    int row = gid >> 7;
    float n = n_f[row];
    float4 e = ((const float4*)embed)[gid];
    float4 w;
    w.x = __fdiv_rn(e.x, n); w.y = __fdiv_rn(e.y, n);
    w.z = __fdiv_rn(e.z, n); w.w = __fdiv_rn(e.w, n);
    ((float4*)whf)[gid] = w;
    ushort4 o;
    o.x = f32_to_bf16_rn(w.x); o.y = f32_to_bf16_rn(w.y);
    o.z = f32_to_bf16_rn(w.z); o.w = f32_to_bf16_rn(w.w);
    ((ushort4*)wb)[gid] = o;
}

// ---------------------------------------------------------------------------
// K3: bf16 MFMA coarse scoring + fused per-token candidate selection.
// Grid: (N_TOK/64)*2 blocks; block b: tokens (b>>1)*64, codes (b&1)*2048..+2048.
// 4 waves; wave w computes the 64x64 strip at cols nt*256 + w*64.
//
// R5: per-thread selection relaxed from exact top-8 (22 VALU/item) to sorted
// top-3 (5 VALU/item). Candidates/token = 4 quarter-threads x 3 keys x 2
// halves = 24, merged to 8 downstream. Containment: the true f32-argmax is
// lost only if >=3 higher-keyed codes share its 512-col thread slice
// (P ~ (0.03)^3/16, negligible) or >=8 global beaters exist (never).
// Keys: [monotone f32 top 20 bits | 4095-code_idx] as in R4 (granularity
// 2^-11 rel << top-gap; inverted idx = smallest-index tie-break).
// Barrier skeleton identical to R3/R4 (verified correct).
__global__ __launch_bounds__(256, 2) void coarse_kernel(
        const unsigned short* __restrict__ xb,
        const unsigned short* __restrict__ wb,
        unsigned* __restrict__ candp) {
    __shared__ __attribute__((aligned(16))) char smem[2 * BUFSZ];

    const int tid  = threadIdx.x;
    const int w    = tid >> 6;         // wave id 0..3
    const int l    = tid & 63;
    const int m0   = (blockIdx.x >> 1) * CBM;
    const int half = blockIdx.x & 1;
    const int n0   = half * NHALF;

    const int srow   = l >> 3;               // row within an 8-row staging group
    const int schunk = (l & 7) ^ srow;       // XOR-swizzled source 16B-chunk
    const int mrow   = l & 15;
    const int kq     = l >> 4;               // 0..3
    const int sw     = mrow & 7;

    // per-lane LDS frag-read byte offsets within a buffer.
    const int aoff0 = mrow * 128 + (kq        ^ sw) * 16;
    const int aoff1 = mrow * 128 + ((kq ^ 4)  ^ sw) * 16;
    const int boff0 = 8192 + w * 8192 + mrow * 128 + (kq       ^ sw) * 16;
    const int boff1 = 8192 + w * 8192 + mrow * 128 + ((kq ^ 4) ^ sw) * 16;

    // per-lane global staging sources (advance gB once per nt)
    const unsigned short* gA0 = xb + (size_t)(m0 + w * 16 +     srow) * DIM + schunk * 8;
    const unsigned short* gA1 = xb + (size_t)(m0 + w * 16 + 8 + srow) * DIM + schunk * 8;
    const unsigned short* gB[8];
#pragma unroll
    for (int c = 0; c < 8; ++c)
        gB[c] = wb + (size_t)(n0 + w * 64 + c * 8 + srow) * DIM + schunk * 8;

    // wave-uniform LDS staging destinations (byte offsets within a buffer)
    const int dA = w * 2048;                 // A rows [w*16, w*16+16)
    const int dB = 8192 + w * 8192;          // B rows [w*64, w*64+64)

    auto STAGE = [&](int dstbuf, int koff) {  // koff in bf16 elements
        char* db = smem + dstbuf * BUFSZ;
        __builtin_amdgcn_global_load_lds(
            (const __attribute__((address_space(1))) void*)(gA0 + koff),
            (__attribute__((address_space(3))) void*)(db + dA), 16, 0, 0);
        __builtin_amdgcn_global_load_lds(
            (const __attribute__((address_space(1))) void*)(gA1 + koff),
            (__attribute__((address_space(3))) void*)(db + dA + 1024), 16, 0, 0);
#pragma unroll
        for (int c = 0; c < 8; ++c)
            __builtin_amdgcn_global_load_lds(
                (const __attribute__((address_space(1))) void*)(gB[c] + koff),
                (__attribute__((address_space(3))) void*)(db + dB + c * 1024), 16, 0, 0);
    };

    // strips (packed u32 keys) in buf1 region; fixed per-thread pointers
    unsigned* const sS  = (unsigned*)(smem + BUFSZ);
    unsigned* const swp = sS + w * (64 * SPITCH) + kq * (4 * SPITCH) + mrow;
    const uint4* const srp = (const uint4*)(sS + (tid >> 6) * (64 * SPITCH) + (tid & 63) * SPITCH);

    // inverted-index base for key packing: idx_field = invb - nt*256 - h*32 - jj*16
    const int invb = 4095 - n0 - w * 64 - mrow;

    unsigned b0 = 0u, b1 = 0u, b2 = 0u;   // sorted top-3 of this thread's slice

    // prologue: stage tile (0,0) into buf0
    STAGE(0, 0);

    for (int nt = 0; nt < NT_STEPS; ++nt) {
        f32x4 acc[4][4];
#pragma unroll
        for (int i = 0; i < 4; ++i)
#pragma unroll
            for (int j = 0; j < 4; ++j) acc[i][j] = {0.0f, 0.0f, 0.0f, 0.0f};

#pragma unroll
        for (int kc = 0; kc < KC_STEPS; ++kc) {
            // top barrier: stage target buf[(kc+1)&1] free of readers (WAR).
            // kc==0: covered by selection's closing BARL (or untouched, nt=0).
            if (kc > 0) BARL();

            // prefetch next tile into the other buffer (issue only; no drain)
            if (kc < KC_STEPS - 1) {
                STAGE((kc + 1) & 1, (kc + 1) * CBK);
                BAR_PUB10();           // tile kc landed; tile kc+1 in flight
            } else if (nt < NT_STEPS - 1) {
#pragma unroll
                for (int c = 0; c < 8; ++c) gB[c] += (size_t)CBN * DIM;
                STAGE(0, 0);
                BAR_PUB10();           // prefetch (nt+1,0) rides through selection
            } else {
                BAR_PUB0();            // final tile: nothing left in flight
            }

            const int bb = (kc & 1) * BUFSZ;
            bf16x8 a0[4], bb0[4], a1[4], bb1[4];
#pragma unroll
            for (int i = 0; i < 4; ++i)
                a0[i] = *(const bf16x8*)(smem + bb + aoff0 + i * 2048);
#pragma unroll
            for (int j = 0; j < 4; ++j)
                bb0[j] = *(const bf16x8*)(smem + bb + boff0 + j * 2048);
#pragma unroll
            for (int i = 0; i < 4; ++i)
#pragma unroll
                for (int j = 0; j < 4; ++j)
                    acc[i][j] = __builtin_amdgcn_mfma_f32_16x16x32_bf16(
                        a0[i], bb0[j], acc[i][j], 0, 0, 0);
#pragma unroll
            for (int i = 0; i < 4; ++i)
                a1[i] = *(const bf16x8*)(smem + bb + aoff1 + i * 2048);
#pragma unroll
            for (int j = 0; j < 4; ++j)
                bb1[j] = *(const bf16x8*)(smem + bb + boff1 + j * 2048);
#pragma unroll
            for (int i = 0; i < 4; ++i)
#pragma unroll
                for (int j = 0; j < 4; ++j)
                    acc[i][j] = __builtin_amdgcn_mfma_f32_16x16x32_bf16(
                        a1[i], bb1[j], acc[i][j], 0, 0, 0);
            // BARL at next iteration's top drains these ds_reads explicitly
            // before any wave may overwrite buf[kc&1].
        }

        // selection: 2 half-strip rounds (32 cols each); strips live in buf1
        // region (tile (nt,7) consumed from buf1; the live prefetched tile
        // (nt+1,0) sits in buf0, untouched). The in-flight prefetch is NOT
        // drained here -- its latency hides under selection.
        BARL();   // all waves' buf1 frag reads drained -> strip writes safe
#pragma unroll
        for (int h = 0; h < 2; ++h) {
#pragma unroll
            for (int i = 0; i < 4; ++i)
#pragma unroll
                for (int jj = 0; jj < 2; ++jj) {
                    const int j = h * 2 + jj;
                    const unsigned ifld = (unsigned)(invb - (nt * 256 + h * 32 + jj * 16));
#pragma unroll
                    for (int r = 0; r < 4; ++r) {
                        unsigned key = (f32_sortkey(acc[i][j][r]) & 0xFFFFF000u) | ifld;
                        swp[(i * 16 + r) * SPITCH + jj * 16] = key;
                    }
                }
            BARL();   // strip writes drained + visible to scanning threads
            // scan: thread (tok = tid&63, qq = tid>>6) scans strip qq's 32
            // packed keys; sorted top-3, 5 min/max VALU per key.
#pragma unroll
            for (int c4 = 0; c4 < 8; ++c4) {
                uint4 v = srp[c4];
                top3k_insert(v.x, b0, b1, b2);
                top3k_insert(v.y, b0, b1, b2);
                top3k_insert(v.z, b0, b1, b2);
                top3k_insert(v.w, b0, b1, b2);
            }
            BARL();   // scan reads drained before strips overwritten / restaged
        }
    }

    // emit this thread's 3 keys: candp[tok][half][qq][0..2]
    {
        int tok = tid & 63, qq = tid >> 6;
        unsigned* cp = candp + ((size_t)(m0 + tok) * 2 + half) * 12 + qq * 3;
        cp[0] = b0; cp[1] = b1; cp[2] = b2;
    }
}

// ---------------------------------------------------------------------------
// K3b: merge the 24 candidate keys/token -> final 8 candidate idx/token.
__global__ void merge_kernel(const unsigned* __restrict__ candp, int* __restrict__ cand8) {
    int tok = blockIdx.x * 256 + threadIdx.x;
    unsigned bv[8];
#pragma unroll
    for (int k = 0; k < 8; ++k) bv[k] = 0u;
    const unsigned* cp = candp + (size_t)tok * 24;
#pragma unroll
    for (int t = 0; t < 24; ++t) top8k_insert(cp[t], bv);
    int* o = cand8 + (size_t)tok * 8;
#pragma unroll
    for (int k = 0; k < 8; ++k) o[k] = 4095 - (int)(bv[k] & 0xFFFu);
}

// ---------------------------------------------------------------------------
// K4: f32-replicated dist over 8 candidates (np-exact), gather + MSE partial.
__global__ void refine_kernel(const float* __restrict__ x,
                              const float* __restrict__ embed,
                              const float* __restrict__ whf,
                              const float* __restrict__ t3_f,
                              const int* __restrict__ cand,
                              float* __restrict__ out,
                              double* __restrict__ partial) {
    __shared__ float part[4][32];
    __shared__ double wsum[4];
    const int wid  = threadIdx.x >> 6;
    const int lane = threadIdx.x & 63;
    const int tok  = blockIdx.x * 4 + wid;
    const float* f = x + (size_t)tok * DIM;

    if (lane < 32) {
        int base = (lane >> 3) * 128 + (lane & 7);
        float v = f[base];
        float r = __fmul_rn(v, v);
#pragma unroll
        for (int i = 1; i < 16; ++i) {
            float u = f[base + 8 * i];
            r = __fadd_rn(r, __fmul_rn(u, u));
        }
        part[wid][lane] = r;
    }
    __syncthreads();
    float t1 = pairwise_tree(part[wid]);

    float4 f0 = *(const float4*)(f + lane * 8);
    float4 f1 = *(const float4*)(f + lane * 8 + 4);

    float bd = 1e30f; int bc = 0x7fffffff;
    const int* cp = cand + (size_t)tok * 8;
#pragma unroll
    for (int k = 0; k < 8; ++k) {
        int c = cp[k];
        const float* wh = whf + (size_t)c * DIM + lane * 8;
        float4 w0 = *(const float4*)wh;
        float4 w1 = *(const float4*)(wh + 4);
        double s = (double)f0.x * w0.x + (double)f0.y * w0.y
                 + (double)f0.z * w0.z + (double)f0.w * w0.w
                 + (double)f1.x * w1.x + (double)f1.y * w1.y
                 + (double)f1.z * w1.z + (double)f1.w * w1.w;
#pragma unroll
        for (int off = 32; off > 0; off >>= 1) s += __shfl_xor(s, off);
        float mm = (float)s;
        float dist = __fadd_rn(__fsub_rn(t1, __fmul_rn(2.0f, mm)), t3_f[c]);
        if (dist < bd || (dist == bd && c < bc)) { bd = dist; bc = c; }
    }

    const float* eb = embed + (size_t)bc * DIM;
    double dsum = 0.0;
#pragma unroll
    for (int r = 0; r < DIM / 64; ++r) {
        int d = lane + 64 * r;
        float q = eb[d];
        out[(size_t)tok * DIM + d] = q;   // (quantize + quantize_1)*0.5 == quantize
        double dd = (double)q - (double)f[d];
        dsum += dd * dd;
    }
#pragma unroll
    for (int off = 32; off > 0; off >>= 1) dsum += __shfl_xor(dsum, off);
    if (lane == 0) wsum[wid] = dsum;
    __syncthreads();
    if (threadIdx.x == 0)
        partial[blockIdx.x] = wsum[0] + wsum[1] + wsum[2] + wsum[3];
}

// ---------------------------------------------------------------------------
__global__ void finalize_kernel(const double* __restrict__ partial,
                                float* __restrict__ out) {
    __shared__ double acc[4];
    int tid = threadIdx.x;
    double s = 0.0;
    for (int i = tid; i < N_TOK / 4; i += 256) s += partial[i];
#pragma unroll
    for (int off = 32; off > 0; off >>= 1) s += __shfl_xor(s, off);
    if ((tid & 63) == 0) acc[tid >> 6] = s;
    __syncthreads();
    if (tid == 0)
        out[(size_t)N_TOK * DIM] =
            (float)((acc[0] + acc[1] + acc[2] + acc[3]) * (1.0 / ((double)N_TOK * DIM)));
}

// ---------------------------------------------------------------------------
extern "C" void kernel_launch(void* const* d_in, const int* in_sizes, int n_in,
                              void* d_out, int out_size, void* d_ws, size_t ws_size,
                              hipStream_t stream) {
    const float* x     = (const float*)d_in[0];   // [32768, 512]
    const float* embed = (const float*)d_in[1];   // [4096, 512]
    float* out = (float*)d_out;                   // 16777216 + 1 floats

    char* wsb = (char*)d_ws;
    size_t off = 0;
    double* partial = (double*)(wsb + off); off += 65536;            // 8192 f64
    float*  n_f     = (float*) (wsb + off); off += 16384;
    float*  t3_f    = (float*) (wsb + off); off += 16384;
    unsigned* candp = (unsigned*)(wsb + off); off += (size_t)N_TOK * 24 * 4;  // 3 MB
    int*    cand8   = (int*)   (wsb + off); off += (size_t)N_TOK * 8 * 4;     // 1 MB
    unsigned short* xb = (unsigned short*)(wsb + off); off += (size_t)N_TOK * DIM * 2;  // 32 MB
    unsigned short* wb = (unsigned short*)(wsb + off); off += (size_t)N_CODE * DIM * 2; // 4 MB
    float*  whf     = (float*) (wsb + off);                                   // 8 MB

    xcvt_kernel    <<<16384, 256, 0, stream>>>(x, xb);
    norms_kernel   <<<N_CODE, 64, 0, stream>>>(embed, n_f, t3_f);
    wcvt_kernel    <<<2048, 256, 0, stream>>>(embed, n_f, whf, wb);
    coarse_kernel  <<<(N_TOK / CBM) * 2, 256, 0, stream>>>(xb, wb, candp);
    merge_kernel   <<<N_TOK / 256, 256, 0, stream>>>(candp, cand8);
    refine_kernel  <<<N_TOK / 4, 256, 0, stream>>>(x, embed, whf, t3_f, cand8, out, partial);
    finalize_kernel<<<1, 256, 0, stream>>>(partial, out);
}

// Round 6
// 368.913 us; speedup vs baseline: 1.4950x; 1.0124x over previous
//
#include <hip/hip_runtime.h>
#include <math.h>

// Problem constants (B=16, T=2048, DIM=512, N_EMBED=4096)
#define N_TOK   32768
#define N_CODE  4096
#define DIM     512

// Coarse MFMA tiling: block = 64 tokens x 2048 codes (one N-half)
#define CBM 64
#define NHALF 2048
#define CBN 256                   // codes per nt step
#define CBK 64                    // K chunk per staging round
#define NT_STEPS (NHALF / CBN)    // 8
#define KC_STEPS (DIM / CBK)      // 8
#define BUFSZ 40960               // one LDS tile buffer: A 8KB + B 32KB

// ---------------------------------------------------------------------------
// Scheduler-movement-proof sync points (rule #18: register-only MFMA/VALU can
// cross inline asm despite "memory" clobber, dragging the compiler's lgkmcnt
// waits with them => a wave can pass a raw s_barrier with ds ops outstanding.
// Fix: sched_barrier(0) fences on both sides + explicit lgkmcnt drain).
#define SFENCE() __builtin_amdgcn_sched_barrier(0)

// drain own LDS ops, then barrier (WAR protection / LDS publish)
#define BARL() do { \
    SFENCE(); \
    asm volatile("s_waitcnt lgkmcnt(0)" ::: "memory"); \
    __builtin_amdgcn_s_barrier(); \
    SFENCE(); \
} while (0)

// publish staged tile: 10 newest vmem ops (next tile's DMA) stay in flight
#define BAR_PUB10() do { \
    SFENCE(); \
    asm volatile("s_waitcnt vmcnt(10)" ::: "memory"); \
    __builtin_amdgcn_s_barrier(); \
    SFENCE(); \
} while (0)

// publish final tile: nothing left in flight
#define BAR_PUB0() do { \
    SFENCE(); \
    asm volatile("s_waitcnt vmcnt(0)" ::: "memory"); \
    __builtin_amdgcn_s_barrier(); \
    SFENCE(); \
} while (0)

typedef __bf16 bf16x8 __attribute__((ext_vector_type(8)));
typedef float  f32x4  __attribute__((ext_vector_type(4)));

__device__ __forceinline__ unsigned short f32_to_bf16_rn(float f) {
    union { float f; unsigned int u; } c; c.f = f;
    unsigned int u = c.u;
    return (unsigned short)((u + 0x7FFFu + ((u >> 16) & 1u)) >> 16);
}

// monotone f32 -> sortable u32 (increasing)
__device__ __forceinline__ unsigned f32_sortkey(float f) {
    unsigned u = __float_as_uint(f);
    return u ^ ((unsigned)(((int)u) >> 31) | 0x80000000u);
}

// ---------------------------------------------------------------------------
// Branchless top-8 over packed u32 keys (coarse tail + merge_kernel).
__device__ __forceinline__ void top8k_insert(unsigned s, unsigned (&bv)[8]) {
#pragma unroll
    for (int k = 7; k > 0; --k) {
        unsigned t = bv[k] > s ? bv[k] : s;          // v_max_u32
        bv[k] = (s > bv[k - 1]) ? bv[k - 1] : t;     // v_cmp + v_cndmask
    }
    bv[0] = bv[0] > s ? bv[0] : s;
}

// Sorted top-3 update, 5 VALU (min/max only), keeps b0>=b1>=b2.
__device__ __forceinline__ void top3k_insert(unsigned s, unsigned &b0,
                                             unsigned &b1, unsigned &b2) {
    unsigned t = b0 < s ? b0 : s;   // min(b0,s)
    b0 = b0 > s ? b0 : s;           // max
    unsigned u = b1 < t ? b1 : t;   // min(b1,t)
    b1 = b1 > t ? b1 : t;           // max
    b2 = b2 > u ? b2 : u;           // max
}

// ---------------------------------------------------------------------------
// numpy pairwise f32 sum over 512 contiguous elements (bit-exact).
__device__ __forceinline__ float pairwise_tree(const float* p) {
    float P[4];
#pragma unroll
    for (int b = 0; b < 4; ++b) {
        float t01 = __fadd_rn(p[b * 8 + 0], p[b * 8 + 1]);
        float t23 = __fadd_rn(p[b * 8 + 2], p[b * 8 + 3]);
        float t45 = __fadd_rn(p[b * 8 + 4], p[b * 8 + 5]);
        float t67 = __fadd_rn(p[b * 8 + 6], p[b * 8 + 7]);
        P[b] = __fadd_rn(__fadd_rn(t01, t23), __fadd_rn(t45, t67));
    }
    return __fadd_rn(__fadd_rn(P[0], P[1]), __fadd_rn(P[2], P[3]));
}

// ---------------------------------------------------------------------------
// K1: per-code f32-replicated norm + t3.
__global__ void norms_kernel(const float* __restrict__ embed,
                             float* __restrict__ n_f,
                             float* __restrict__ t3_f) {
    __shared__ float part[32];
    int j = blockIdx.x;
    int lane = threadIdx.x;
    const float* e = embed + (size_t)j * DIM;

    if (lane < 32) {
        int base = (lane >> 3) * 128 + (lane & 7);
        float v = e[base];
        float r = __fmul_rn(v, v);
#pragma unroll
        for (int i = 1; i < 16; ++i) {
            float u = e[base + 8 * i];
            r = __fadd_rn(r, __fmul_rn(u, u));
        }
        part[lane] = r;
    }
    __syncthreads();
    float S = pairwise_tree(part);
    float n = __fsqrt_rn(S);
    __syncthreads();

    if (lane < 32) {
        int base = (lane >> 3) * 128 + (lane & 7);
        float w0 = __fdiv_rn(e[base], n);
        float r = __fmul_rn(w0, w0);
#pragma unroll
        for (int i = 1; i < 16; ++i) {
            float w = __fdiv_rn(e[base + 8 * i], n);
            r = __fadd_rn(r, __fmul_rn(w, w));
        }
        part[lane] = r;
    }
    __syncthreads();
    if (lane == 0) {
        n_f[j]  = n;
        t3_f[j] = pairwise_tree(part);
    }
}

// ---------------------------------------------------------------------------
// K2a: x -> bf16 (RN)
__global__ void xcvt_kernel(const float* __restrict__ x, unsigned short* __restrict__ xb) {
    int gid = blockIdx.x * 256 + threadIdx.x;
    float4 v = ((const float4*)x)[gid];
    ushort4 o;
    o.x = f32_to_bf16_rn(v.x); o.y = f32_to_bf16_rn(v.y);
    o.z = f32_to_bf16_rn(v.z); o.w = f32_to_bf16_rn(v.w);
    ((ushort4*)xb)[gid] = o;
}

// K2b: w_hat = e/n (f32, np-exact) -> f32 (refine) + bf16 (coarse)
__global__ void wcvt_kernel(const float* __restrict__ embed, const float* __restrict__ n_f,
                            float* __restrict__ whf, unsigned short* __restrict__ wb) {
    int gid = blockIdx.x * 256 + threadIdx.x;
    int row = gid >> 7;
    float n = n_f[row];
    float4 e = ((const float4*)embed)[gid];
    float4 w;
    w.x = __fdiv_rn(e.x, n); w.y = __fdiv_rn(e.y, n);
    w.z = __fdiv_rn(e.z, n); w.w = __fdiv_rn(e.w, n);
    ((float4*)whf)[gid] = w;
    ushort4 o;
    o.x = f32_to_bf16_rn(w.x); o.y = f32_to_bf16_rn(w.y);
    o.z = f32_to_bf16_rn(w.z); o.w = f32_to_bf16_rn(w.w);
    ((ushort4*)wb)[gid] = o;
}

// ---------------------------------------------------------------------------
// K3: bf16 MFMA coarse scoring + fully in-register per-token selection.
// Grid: (N_TOK/64)*2 blocks; block b: tokens (b>>1)*64, codes (b&1)*2048..+2048.
// 4 waves; wave w covers the 64-code strip at cols nt*256 + w*64.
//
// R6: SWAPPED-OPERAND MFMA (T12 insight: make the reduction axis lane-local).
// acc[i][j] = mfma(b_frag[j], a_frag[i], acc) gives the transposed tile:
//   col = lane&15  -> TOKEN (i*16 + mrow)
//   row = (lane>>4)*4 + r -> CODE (j*16 + kq*4 + r)
// so each lane owns 4 tokens x 16 codes per nt and top-3 selection runs on
// acc registers directly -- no LDS strip, no selection barriers (was 5/nt +
// 64 ds_write + 16 ds_read_b128 per nt). Slices shrink to 128 codes/thread
// (x8 nt): containment of the true f32-argmax needs it top-3 of its 128-slice
// by 20-bit bf16 key -- P(fail) ~1e-10/token. Block tail compacts the
// 48 keys/token/half to 8 via one LDS pass (candp stays 2MB as in R4/R5).
// Keys: [monotone f32 top 20 bits | 4095-code] (smallest-index tie-break).
// kc-loop barrier skeleton identical to R3-R5 (verified correct).
__global__ __launch_bounds__(256, 2) void coarse_kernel(
        const unsigned short* __restrict__ xb,
        const unsigned short* __restrict__ wb,
        unsigned* __restrict__ candp) {
    __shared__ __attribute__((aligned(16))) char smem[2 * BUFSZ];

    const int tid  = threadIdx.x;
    const int w    = tid >> 6;         // wave id 0..3
    const int l    = tid & 63;
    const int m0   = (blockIdx.x >> 1) * CBM;
    const int half = blockIdx.x & 1;
    const int n0   = half * NHALF;

    const int srow   = l >> 3;               // row within an 8-row staging group
    const int schunk = (l & 7) ^ srow;       // XOR-swizzled source 16B-chunk
    const int mrow   = l & 15;               // token-low (C col) / frag row
    const int kq     = l >> 4;               // lane group 0..3 (code sub-row)
    const int sw     = mrow & 7;

    // per-lane LDS frag-read byte offsets within a buffer.
    const int aoff0 = mrow * 128 + (kq        ^ sw) * 16;
    const int aoff1 = mrow * 128 + ((kq ^ 4)  ^ sw) * 16;
    const int boff0 = 8192 + w * 8192 + mrow * 128 + (kq       ^ sw) * 16;
    const int boff1 = 8192 + w * 8192 + mrow * 128 + ((kq ^ 4) ^ sw) * 16;

    // per-lane global staging sources (advance gB once per nt)
    const unsigned short* gA0 = xb + (size_t)(m0 + w * 16 +     srow) * DIM + schunk * 8;
    const unsigned short* gA1 = xb + (size_t)(m0 + w * 16 + 8 + srow) * DIM + schunk * 8;
    const unsigned short* gB[8];
#pragma unroll
    for (int c = 0; c < 8; ++c)
        gB[c] = wb + (size_t)(n0 + w * 64 + c * 8 + srow) * DIM + schunk * 8;

    // wave-uniform LDS staging destinations (byte offsets within a buffer)
    const int dA = w * 2048;                 // A rows [w*16, w*16+16)
    const int dB = 8192 + w * 8192;          // B rows [w*64, w*64+64)

    auto STAGE = [&](int dstbuf, int koff) {  // koff in bf16 elements
        char* db = smem + dstbuf * BUFSZ;
        __builtin_amdgcn_global_load_lds(
            (const __attribute__((address_space(1))) void*)(gA0 + koff),
            (__attribute__((address_space(3))) void*)(db + dA), 16, 0, 0);
        __builtin_amdgcn_global_load_lds(
            (const __attribute__((address_space(1))) void*)(gA1 + koff),
            (__attribute__((address_space(3))) void*)(db + dA + 1024), 16, 0, 0);
#pragma unroll
        for (int c = 0; c < 8; ++c)
            __builtin_amdgcn_global_load_lds(
                (const __attribute__((address_space(1))) void*)(gB[c] + koff),
                (__attribute__((address_space(3))) void*)(db + dB + c * 1024), 16, 0, 0);
    };

    // per-thread selection state: token slot i (token = m0 + i*16 + mrow),
    // sorted top-3 keys over this lane's code slice.
    unsigned k0[4], k1[4], k2[4];
#pragma unroll
    for (int i = 0; i < 4; ++i) { k0[i] = 0u; k1[i] = 0u; k2[i] = 0u; }

    // prologue: stage tile (0,0) into buf0
    STAGE(0, 0);

    for (int nt = 0; nt < NT_STEPS; ++nt) {
        f32x4 acc[4][4];
#pragma unroll
        for (int i = 0; i < 4; ++i)
#pragma unroll
            for (int j = 0; j < 4; ++j) acc[i][j] = {0.0f, 0.0f, 0.0f, 0.0f};

#pragma unroll
        for (int kc = 0; kc < KC_STEPS; ++kc) {
            // top barrier: stage target buf[(kc+1)&1] free of readers (WAR).
            // nt=0,kc=0: buf1 untouched -> skip.
            if (kc > 0) { BARL(); }
            else if (nt > 0) { BARL(); }

            // prefetch next tile into the other buffer (issue only; no drain)
            if (kc < KC_STEPS - 1) {
                STAGE((kc + 1) & 1, (kc + 1) * CBK);
                BAR_PUB10();           // tile kc landed; tile kc+1 in flight
            } else if (nt < NT_STEPS - 1) {
#pragma unroll
                for (int c = 0; c < 8; ++c) gB[c] += (size_t)CBN * DIM;
                STAGE(0, 0);
                BAR_PUB10();           // prefetch (nt+1,0) rides through selection
            } else {
                BAR_PUB0();            // final tile: nothing left in flight
            }

            const int bb = (kc & 1) * BUFSZ;
            bf16x8 a0[4], bb0[4], a1[4], bb1[4];
#pragma unroll
            for (int i = 0; i < 4; ++i)
                a0[i] = *(const bf16x8*)(smem + bb + aoff0 + i * 2048);
#pragma unroll
            for (int j = 0; j < 4; ++j)
                bb0[j] = *(const bf16x8*)(smem + bb + boff0 + j * 2048);
            // swapped operands: D[code][token] (col=token, row=code)
#pragma unroll
            for (int i = 0; i < 4; ++i)
#pragma unroll
                for (int j = 0; j < 4; ++j)
                    acc[i][j] = __builtin_amdgcn_mfma_f32_16x16x32_bf16(
                        bb0[j], a0[i], acc[i][j], 0, 0, 0);
#pragma unroll
            for (int i = 0; i < 4; ++i)
                a1[i] = *(const bf16x8*)(smem + bb + aoff1 + i * 2048);
#pragma unroll
            for (int j = 0; j < 4; ++j)
                bb1[j] = *(const bf16x8*)(smem + bb + boff1 + j * 2048);
#pragma unroll
            for (int i = 0; i < 4; ++i)
#pragma unroll
                for (int j = 0; j < 4; ++j)
                    acc[i][j] = __builtin_amdgcn_mfma_f32_16x16x32_bf16(
                        bb1[j], a1[i], acc[i][j], 0, 0, 0);
            // next top-BARL drains these ds_reads before buf reuse.
        }

        // in-register selection, barrier-free: this lane's scores are
        // score(token = m0 + i*16 + mrow, code = n0 + nt*256 + w*64 +
        // j*16 + kq*4 + r) = acc[i][j][r]. Pack 20-bit key + inverted
        // 12-bit code, sorted top-3 per token slot. The (nt+1,0) prefetch
        // (vmcnt rides) lands underneath this VALU work.
        {
            const unsigned inb = (unsigned)(4095 - n0 - w * 64 - kq * 4 - nt * 256);
#pragma unroll
            for (int i = 0; i < 4; ++i)
#pragma unroll
                for (int j = 0; j < 4; ++j)
#pragma unroll
                    for (int r = 0; r < 4; ++r) {
                        unsigned key = (f32_sortkey(acc[i][j][r]) & 0xFFFFF000u)
                                     | (inb - (unsigned)(j * 16 + r));
                        top3k_insert(key, k0[i], k1[i], k2[i]);
                    }
        }
    }

    // block tail: compact 16 slots x 3 keys -> top-8 per token-half.
    // buf0 region free: last buf0 read was tile (7,6); kc=7's top BARL
    // drained it, and the final tile lives in buf1.
    {
        unsigned* ck = (unsigned*)smem;          // [64 tok][16 slot][3]
        const int slot = w * 4 + kq;
#pragma unroll
        for (int i = 0; i < 4; ++i) {
            unsigned* p = ck + ((size_t)(i * 16 + mrow) * 16 + slot) * 3;
            p[0] = k0[i]; p[1] = k1[i]; p[2] = k2[i];
        }
    }
    BARL();
    if (tid < 64) {
        const uint4* cq = (const uint4*)smem + tid * 12;   // 48 u32 = 12 uint4
        unsigned fv[8];
#pragma unroll
        for (int k = 0; k < 8; ++k) fv[k] = 0u;
#pragma unroll
        for (int t = 0; t < 12; ++t) {
            uint4 v = cq[t];
            top8k_insert(v.x, fv);
            top8k_insert(v.y, fv);
            top8k_insert(v.z, fv);
            top8k_insert(v.w, fv);
        }
        unsigned* cp = candp + ((size_t)(m0 + tid) * 2 + half) * 8;
#pragma unroll
        for (int k = 0; k < 8; ++k) cp[k] = fv[k];
    }
}

// ---------------------------------------------------------------------------
// K3b: merge the two halves' top-8 key lists -> final 8 candidate idx/token.
__global__ void merge_kernel(const unsigned* __restrict__ candp, int* __restrict__ cand8) {
    int tok = blockIdx.x * 256 + threadIdx.x;
    unsigned bv[8];
#pragma unroll
    for (int k = 0; k < 8; ++k) bv[k] = 0u;
    const unsigned* cp = candp + (size_t)tok * 16;
#pragma unroll
    for (int t = 0; t < 16; ++t) top8k_insert(cp[t], bv);
    int* o = cand8 + (size_t)tok * 8;
#pragma unroll
    for (int k = 0; k < 8; ++k) o[k] = 4095 - (int)(bv[k] & 0xFFFu);
}

// ---------------------------------------------------------------------------
// K4: f32-replicated dist over 8 candidates (np-exact), gather + MSE partial.
__global__ void refine_kernel(const float* __restrict__ x,
                              const float* __restrict__ embed,
                              const float* __restrict__ whf,
                              const float* __restrict__ t3_f,
                              const int* __restrict__ cand,
                              float* __restrict__ out,
                              double* __restrict__ partial) {
    __shared__ float part[4][32];
    __shared__ double wsum[4];
    const int wid  = threadIdx.x >> 6;
    const int lane = threadIdx.x & 63;
    const int tok  = blockIdx.x * 4 + wid;
    const float* f = x + (size_t)tok * DIM;

    if (lane < 32) {
        int base = (lane >> 3) * 128 + (lane & 7);
        float v = f[base];
        float r = __fmul_rn(v, v);
#pragma unroll
        for (int i = 1; i < 16; ++i) {
            float u = f[base + 8 * i];
            r = __fadd_rn(r, __fmul_rn(u, u));
        }
        part[wid][lane] = r;
    }
    __syncthreads();
    float t1 = pairwise_tree(part[wid]);

    float4 f0 = *(const float4*)(f + lane * 8);
    float4 f1 = *(const float4*)(f + lane * 8 + 4);

    float bd = 1e30f; int bc = 0x7fffffff;
    const int* cp = cand + (size_t)tok * 8;
#pragma unroll
    for (int k = 0; k < 8; ++k) {
        int c = cp[k];
        const float* wh = whf + (size_t)c * DIM + lane * 8;
        float4 w0 = *(const float4*)wh;
        float4 w1 = *(const float4*)(wh + 4);
        double s = (double)f0.x * w0.x + (double)f0.y * w0.y
                 + (double)f0.z * w0.z + (double)f0.w * w0.w
                 + (double)f1.x * w1.x + (double)f1.y * w1.y
                 + (double)f1.z * w1.z + (double)f1.w * w1.w;
#pragma unroll
        for (int off = 32; off > 0; off >>= 1) s += __shfl_xor(s, off);
        float mm = (float)s;
        float dist = __fadd_rn(__fsub_rn(t1, __fmul_rn(2.0f, mm)), t3_f[c]);
        if (dist < bd || (dist == bd && c < bc)) { bd = dist; bc = c; }
    }

    const float* eb = embed + (size_t)bc * DIM;
    double dsum = 0.0;
#pragma unroll
    for (int r = 0; r < DIM / 64; ++r) {
        int d = lane + 64 * r;
        float q = eb[d];
        out[(size_t)tok * DIM + d] = q;   // (quantize + quantize_1)*0.5 == quantize
        double dd = (double)q - (double)f[d];
        dsum += dd * dd;
    }
#pragma unroll
    for (int off = 32; off > 0; off >>= 1) dsum += __shfl_xor(dsum, off);
    if (lane == 0) wsum[wid] = dsum;
    __syncthreads();
    if (threadIdx.x == 0)
        partial[blockIdx.x] = wsum[0] + wsum[1] + wsum[2] + wsum[3];
}

// ---------------------------------------------------------------------------
__global__ void finalize_kernel(const double* __restrict__ partial,
                                float* __restrict__ out) {
    __shared__ double acc[4];
    int tid = threadIdx.x;
    double s = 0.0;
    for (int i = tid; i < N_TOK / 4; i += 256) s += partial[i];
#pragma unroll
    for (int off = 32; off > 0; off >>= 1) s += __shfl_xor(s, off);
    if ((tid & 63) == 0) acc[tid >> 6] = s;
    __syncthreads();
    if (tid == 0)
        out[(size_t)N_TOK * DIM] =
            (float)((acc[0] + acc[1] + acc[2] + acc[3]) * (1.0 / ((double)N_TOK * DIM)));
}

// ---------------------------------------------------------------------------
extern "C" void kernel_launch(void* const* d_in, const int* in_sizes, int n_in,
                              void* d_out, int out_size, void* d_ws, size_t ws_size,
                              hipStream_t stream) {
    const float* x     = (const float*)d_in[0];   // [32768, 512]
    const float* embed = (const float*)d_in[1];   // [4096, 512]
    float* out = (float*)d_out;                   // 16777216 + 1 floats

    char* wsb = (char*)d_ws;
    size_t off = 0;
    double* partial = (double*)(wsb + off); off += 65536;            // 8192 f64
    float*  n_f     = (float*) (wsb + off); off += 16384;
    float*  t3_f    = (float*) (wsb + off); off += 16384;
    unsigned* candp = (unsigned*)(wsb + off); off += (size_t)N_TOK * 16 * 4;  // 2 MB
    int*    cand8   = (int*)   (wsb + off); off += (size_t)N_TOK * 8 * 4;     // 1 MB
    unsigned short* xb = (unsigned short*)(wsb + off); off += (size_t)N_TOK * DIM * 2;  // 32 MB
    unsigned short* wb = (unsigned short*)(wsb + off); off += (size_t)N_CODE * DIM * 2; // 4 MB
    float*  whf     = (float*) (wsb + off);                                   // 8 MB

    xcvt_kernel    <<<16384, 256, 0, stream>>>(x, xb);
    norms_kernel   <<<N_CODE, 64, 0, stream>>>(embed, n_f, t3_f);
    wcvt_kernel    <<<2048, 256, 0, stream>>>(embed, n_f, whf, wb);
    coarse_kernel  <<<(N_TOK / CBM) * 2, 256, 0, stream>>>(xb, wb, candp);
    merge_kernel   <<<N_TOK / 256, 256, 0, stream>>>(candp, cand8);
    refine_kernel  <<<N_TOK / 4, 256, 0, stream>>>(x, embed, whf, t3_f, cand8, out, partial);
    finalize_kernel<<<1, 256, 0, stream>>>(partial, out);
}